// Round 9
// baseline (136.897 us; speedup 1.0000x reference)
//
#include <hip/hip_runtime.h>
#include <math.h>

// FourierBasisTRF: out[b,o,i,w,s] = a[b,s] * ( coefs[o,i,0]*const0
//                    + sum_n basis_n(b,w,s) * norm * coefs[o,i,1+n] )
// T=80, t_emb=w, basis [sin(1t),cos(1t),...,sin(8t),cos(8t)],
// t = (2*pi/80)*c[b,s]*(w - b[b,s]).
//
// R9: CONTIGUOUS-STREAM restructure. R5..R8 showed the scattered shape
// (64 x 4KB fragments @1.04MB stride per block) caps at ~5.0 TB/s vs the
// fill kernel's 6.7 TB/s sequential streams; no reordering helped.
//  - Block = (b, o, i, w-chunk): output [wchunk][4096] is CONTIGUOUS
//    (~260KB sequential stream per block). 2048 blocks.
//  - oi fixed per block -> all 17 coefs are loop-invariant SGPRs.
//  - Basis per element via two recurrences (no per-element sincos):
//      theta(w+1) = theta(w) + K*c   -> 4-FMA rotation per s-col per w
//      s_n = 2c1*s_{n-1} - s_{n-2}   -> 1 FMA per harmonic value (Chebyshev)
//    ~35 VALU ops/element -> ~61us chip VALU, under the ~84us write floor.
//  - Thread t owns s-cols {j*1024 + t*4 ..+3, j=0..3}: per store instr the
//    wave writes 1KB lane-contiguous; block covers each 16KB w-row fully,
//    rows advance sequentially.
//  - XCD chunking: 2048 = 8*256, XCD x <-> b=x (reads and writes XCD-local).

constexpr int S_LEN = 4096;
constexpr int W_LEN = 65;
constexpr int NCOEF = 17;

using f4 = __attribute__((ext_vector_type(4))) float;

__global__ __launch_bounds__(256)
void fourier_basis_trf_kernel(const float* __restrict__ a,
                              const float* __restrict__ b,
                              const float* __restrict__ c,
                              const float* __restrict__ coefs,
                              float* __restrict__ out)
{
    const int tid = threadIdx.x;

    // XCD-chunked remap (bijective on 2048 = 8*256): XCD x gets bb = x.
    const int hw = blockIdx.x;
    const int lg = (hw & 7) * 256 + (hw >> 3);
    const int bb   = lg >> 8;        // 0..7
    const int rest = lg & 255;
    const int oi   = rest >> 2;      // 0..63
    const int wc   = rest & 3;       // w-chunk: [0,17) [17,33) [33,49) [49,65)
    const int w0   = wc * 16 + (wc ? 1 : 0);
    const int nw   = wc ? 16 : 17;

    const float K    = 6.283185307179586f / 80.0f;    // 2*pi/T
    const float NORM = 0.15811388300841897f;          // 1/sqrt(40)
    const float RS2  = 0.7071067811865476f;           // 1/sqrt(2)

    // oi fixed for the whole block -> wave-uniform scalar loads, hoisted.
    const float* cw = coefs + oi * NCOEF;
    const float dterm = cw[0] * RS2;

    // Per-thread state: 16 s-columns (4 groups j of 4).
    float sA[16];                    // a * norm
    float sT[16], cT[16];            // sin/cos of theta(w) per col
    float sD[16], cD[16];            // sin/cos of per-w step K*c per col

    #pragma unroll
    for (int j = 0; j < 4; ++j) {
        const int abi = bb * S_LEN + j * 1024 + tid * 4;
        const f4 av = *reinterpret_cast<const f4*>(a + abi);
        const f4 bv = *reinterpret_cast<const f4*>(b + abi);
        const f4 cv = *reinterpret_cast<const f4*>(c + abi);
        #pragma unroll
        for (int k = 0; k < 4; ++k) {
            const int col = j * 4 + k;
            const float cc  = cv[k];
            const float th0 = K * cc * ((float)w0 - bv[k]);
            const float de  = K * cc;
            sincosf(th0, &sT[col], &cT[col]);
            sincosf(de,  &sD[col], &cD[col]);
            sA[col] = av[k] * NORM;
        }
    }

    // Output: contiguous [nw][4096] slab starting at (bb,oi,w0).
    float* op = out + ((size_t)(bb * 64 + oi) * W_LEN + w0) * S_LEN + tid * 4;

    #pragma unroll 1
    for (int w = 0; w < nw; ++w) {
        f4 r[4];
        #pragma unroll
        for (int col = 0; col < 16; ++col) {
            const float s1 = sT[col];
            const float c1 = cT[col];
            const float two_c1 = c1 + c1;

            // dot( [sin1,cos1,...,sin8,cos8], cw[1..16] ) via Chebyshev
            float acc = dterm;
            acc = fmaf(s1, cw[1], acc);
            acc = fmaf(c1, cw[2], acc);
            float s2 = two_c1 * s1;                 // sin2 (s0 = 0)
            float c2 = fmaf(two_c1, c1, -1.0f);     // cos2
            acc = fmaf(s2, cw[3], acc);
            acc = fmaf(c2, cw[4], acc);
            float spp = s1, sp = s2, cpp = c1, cp = c2;
            #pragma unroll
            for (int n = 3; n <= 8; ++n) {
                const float sn = fmaf(two_c1, sp, -spp);
                const float cn = fmaf(two_c1, cp, -cpp);
                acc = fmaf(sn, cw[2 * n - 1], acc);
                acc = fmaf(cn, cw[2 * n],     acc);
                spp = sp; sp = sn;
                cpp = cp; cp = cn;
            }
            r[col >> 2][col & 3] = acc * sA[col];

            // advance theta by delta: rotation
            sT[col] = fmaf(s1, cD[col],  c1 * sD[col]);
            cT[col] = fmaf(c1, cD[col], -(s1 * sD[col]));
        }
        #pragma unroll
        for (int j = 0; j < 4; ++j)
            *reinterpret_cast<f4*>(op + j * 1024) = r[j];
        op += S_LEN;
    }
}

extern "C" void kernel_launch(void* const* d_in, const int* in_sizes, int n_in,
                              void* d_out, int out_size, void* d_ws, size_t ws_size,
                              hipStream_t stream)
{
    const float* a     = (const float*)d_in[0];
    const float* b     = (const float*)d_in[1];
    const float* c     = (const float*)d_in[2];
    const float* coefs = (const float*)d_in[3];
    float* out = (float*)d_out;

    // 2048 blocks = 8 b * 64 oi * 4 w-chunks; 256 threads each.
    const dim3 grid(2048);
    const dim3 block(256);
    fourier_basis_trf_kernel<<<grid, block, 0, stream>>>(a, b, c, coefs, out);
}

// Round 10
// 109.191 us; speedup vs baseline: 1.2537x; 1.2537x over previous
//
#include <hip/hip_runtime.h>
#include <math.h>

// FourierBasisTRF: out[b,o,i,w,s] = a[b,s] * ( coefs[o,i,0]*const0
//                    + sum_n basis_n(b,w,s) * norm * coefs[o,i,1+n] )
// T=80, t_emb=w (w in [0,65)), basis interleaved [sin(1t),cos(1t),sin(2t),...],
// t = (2*pi/80) * c[b,s] * (w - b[b,s]).
// Algebra: const0 = norm/sqrt(2) ->
//   out = (a*norm) * ( coefs[oi,0]/sqrt(2) + sum_n coefs[oi,1+n]*bas_n )
//
// R10 = R5 verbatim (best: 109.0us). Final ledger of levers tried on top of
// this structure: nt stores +3.6% (R4 kept? no - R5 reverted nt, +1.7% more),
// XCD swizzle +1.7%, 520 fat blocks -24% (R6), wave-phase sync 0% (R7),
// oi stagger -4% (R8), contiguous-stream restructure -26% (R9, compute-bound).
// Structure: 2080 blocks x 256 thr; block = (b, w, s-quarter); 4 s/thread;
// basis via 1 sincos + angle-addition recurrence, amortized over 64 oi;
// coefs read wave-uniform -> SGPR; f4 stores through L2; XCD-chunked swizzle.
// Effective write BW 5.0 TB/s = the practical ceiling for this 64-stream
// scattered write shape (fill kernel's 6.7 TB/s needs sequential streams,
// which R9 showed costs 2x compute to produce).

constexpr int S_LEN = 4096;
constexpr int W_LEN = 65;
constexpr int NOI   = 64;   // nOut * nIn
constexpr int NB    = 16;   // 2 * maxN
constexpr int NCOEF = 17;

using f4 = __attribute__((ext_vector_type(4))) float;

__global__ __launch_bounds__(256)
void fourier_basis_trf_kernel(const float* __restrict__ a,
                              const float* __restrict__ b,
                              const float* __restrict__ c,
                              const float* __restrict__ coefs,
                              float* __restrict__ out)
{
    const int tid = threadIdx.x;

    // XCD-chunked swizzle: hw blocks round-robin over 8 XCDs; give XCD x the
    // logical range [x*260, (x+1)*260). 2080 = 8*260 exactly (bijective).
    const int hw  = blockIdx.x;
    const int blk = (hw & 7) * 260 + (hw >> 3);

    const int schunk = blk & 3;          // 4 chunks of 1024 s per (b,w) row
    const int rest   = blk >> 2;         // = bb*W_LEN + w
    const int w      = rest % W_LEN;
    const int bb     = rest / W_LEN;
    const int s0     = (schunk * 256 + tid) * 4;

    const int abi = bb * S_LEN + s0;
    const f4 av = *reinterpret_cast<const f4*>(a + abi);
    const f4 bv = *reinterpret_cast<const f4*>(b + abi);
    const f4 cv = *reinterpret_cast<const f4*>(c + abi);

    const float tf   = (float)w;                      // TMIN = 0
    const float K    = 6.283185307179586f / 80.0f;    // 2*pi/T
    const float NORM = 0.15811388300841897f;          // 1/sqrt(40)
    const float RS2  = 0.7071067811865476f;           // 1/sqrt(2)

    const float a0 = av.x * NORM;
    const float a1 = av.y * NORM;
    const float a2 = av.z * NORM;
    const float a3 = av.w * NORM;

    // Raw sin/cos harmonics (norm folded into a0..a3).
    float bas[NB][4];
    {
        const float xv[4] = { cv.x * (tf - bv.x), cv.y * (tf - bv.y),
                              cv.z * (tf - bv.z), cv.w * (tf - bv.w) };
        #pragma unroll
        for (int j = 0; j < 4; ++j) {
            float sn, cs;
            sincosf(K * xv[j], &sn, &cs);
            bas[0][j] = sn;
            bas[1][j] = cs;
            float sk = sn, ck = cs;
            #pragma unroll
            for (int k = 1; k < 8; ++k) {
                const float s2 = fmaf(sk, cs,  ck * sn);
                const float c2 = fmaf(ck, cs, -sk * sn);
                bas[2 * k][j]     = s2;
                bas[2 * k + 1][j] = c2;
                sk = s2;
                ck = c2;
            }
        }
    }

    // out flat index: (((bb*8+o)*8+i)*65 + w)*4096 + s ; oi = o*8+i
    float* outp = out + ((size_t)bb * NOI * W_LEN + w) * S_LEN + s0;
    constexpr size_t OI_STRIDE = (size_t)W_LEN * S_LEN;  // 266240

    #pragma unroll 2
    for (int oi = 0; oi < NOI; ++oi) {
        const float* cw = coefs + oi * NCOEF;   // wave-uniform -> s_load
        const float d = cw[0] * RS2;
        float x0 = d, x1 = d, x2 = d, x3 = d;
        #pragma unroll
        for (int n = 0; n < NB; ++n) {
            const float cn = cw[1 + n];
            x0 = fmaf(bas[n][0], cn, x0);
            x1 = fmaf(bas[n][1], cn, x1);
            x2 = fmaf(bas[n][2], cn, x2);
            x3 = fmaf(bas[n][3], cn, x3);
        }
        f4 r;
        r.x = x0 * a0;
        r.y = x1 * a1;
        r.z = x2 * a2;
        r.w = x3 * a3;
        *reinterpret_cast<f4*>(outp + (size_t)oi * OI_STRIDE) = r;
    }
}

extern "C" void kernel_launch(void* const* d_in, const int* in_sizes, int n_in,
                              void* d_out, int out_size, void* d_ws, size_t ws_size,
                              hipStream_t stream)
{
    const float* a     = (const float*)d_in[0];
    const float* b     = (const float*)d_in[1];
    const float* c     = (const float*)d_in[2];
    const float* coefs = (const float*)d_in[3];
    float* out = (float*)d_out;

    // grid: B * W * (S / (4*256)) = 8 * 65 * 4 = 2080 blocks
    const dim3 grid(8 * W_LEN * 4);
    const dim3 block(256);
    fourier_basis_trf_kernel<<<grid, block, 0, stream>>>(a, b, c, coefs, out);
}